// Round 4
// baseline (257.729 us; speedup 1.0000x reference)
//
#include <hip/hip_runtime.h>
#include <hip/hip_bf16.h>

// DCNv2 inception, R4: latency-attack.
// - Block = 256 thr = 4 waves per (16-px tile, branch). Waves split taps
//   stride-4 (balances 9/25/49 within a block), partial-accumulate, then
//   LDS-reduce + coalesced float4 stores.
// - Per wave: manual 2-deep software pipeline — offsets prefetched 2 taps
//   ahead, 8 corner-gathers issued 1 tap ahead into ping-pong register
//   sets, so gather latency hides under the previous tap's lerp+MFMA.
// - xTb: x as [B][H][W][C] bf16; wp: weights bf16 [k][o][c]; one merged
//   prep kernel (fewer launches).

typedef __attribute__((ext_vector_type(8))) short bf16x8;
typedef __attribute__((ext_vector_type(8))) unsigned short u16x8;
typedef __attribute__((ext_vector_type(4))) float f32x4;

__device__ __forceinline__ float b2f(unsigned short u) {
    return __uint_as_float(((unsigned)u) << 16);
}
__device__ __forceinline__ unsigned short f2bf(float f) {
    __hip_bfloat16 h = __float2bfloat16(f);
    return *reinterpret_cast<unsigned short*>(&h);
}

// Merged prep: blocks [0,256): x[b][c][h][w] f32 -> xTb[b][h][w][c] bf16;
// blocks [256,1584): f[o][c][k] f32 -> wp[k][o][c] bf16 (all 3 filters).
__global__ __launch_bounds__(256) void k_prep(
    const float* __restrict__ x,
    const float* __restrict__ f1, const float* __restrict__ f2, const float* __restrict__ f3,
    unsigned short* __restrict__ xTb,
    unsigned short* __restrict__ wp1, unsigned short* __restrict__ wp2, unsigned short* __restrict__ wp3) {
    __shared__ float tile[64][65];
    int bid = blockIdx.x;
    int tid = threadIdx.x;
    if (bid < 256) {
        int b = bid >> 6, h = bid & 63;
        {
            int w = tid & 63, c4 = tid >> 6;
            const float* xp = x + (((b * 64) * 64 + h) * 64) + w;
            #pragma unroll
            for (int i = 0; i < 16; ++i) {
                int c = c4 * 16 + i;
                tile[c][w] = xp[c * 4096];
            }
        }
        __syncthreads();
        {
            int c = tid & 63, w4 = tid >> 6;
            unsigned short* op = xTb + (((b * 64 + h) * 64) * 64) + c;
            #pragma unroll
            for (int i = 0; i < 16; ++i) {
                int ww = w4 * 16 + i;
                op[ww * 64] = f2bf(tile[c][ww]);
            }
        }
    } else {
        int idx = (bid - 256) * 256 + tid;      // 83*4096 = 339968 total
        const float* f; unsigned short* wp; int K, rel;
        if (idx < 36864)       { f = f1; wp = wp1; K = 9;  rel = idx; }
        else if (idx < 139264) { f = f2; wp = wp2; K = 25; rel = idx - 36864; }
        else                   { f = f3; wp = wp3; K = 49; rel = idx - 139264; }
        int c = rel & 63;
        int o = (rel >> 6) & 63;
        int k = rel >> 12;
        wp[rel] = f2bf(f[(o * 64 + c) * K + k]);
    }
}

__global__ __launch_bounds__(256, 3) void k_dcn(
    const unsigned short* __restrict__ xTb,
    const float* __restrict__ off1, const float* __restrict__ msk1, const unsigned short* __restrict__ wp1,
    const float* __restrict__ off2, const float* __restrict__ msk2, const unsigned short* __restrict__ wp2,
    const float* __restrict__ off3, const float* __restrict__ msk3, const unsigned short* __restrict__ wp3,
    float* __restrict__ out) {

    __shared__ __align__(16) float red[4096];   // [wv][ct][l16][quad][r] = 16 KB

    int bb     = blockIdx.x;
    int branch = bb % 3;
    int tile   = bb / 3;          // 0..1023, 16 pixels
    int pix0   = tile << 4;
    int b  = pix0 >> 12;
    int h  = (pix0 >> 6) & 63;
    int w0 = pix0 & 63;

    const float* off; const float* msk; const unsigned short* wp;
    int K, kwid, pad, obase;
    if (branch == 0)      { off = off1; msk = msk1; wp = wp1; K = 9;  kwid = 3; pad = 1; obase = 0;   }
    else if (branch == 1) { off = off2; msk = msk2; wp = wp2; K = 25; kwid = 5; pad = 2; obase = 64;  }
    else                  { off = off3; msk = msk3; wp = wp3; K = 49; kwid = 7; pad = 3; obase = 128; }

    int tid  = threadIdx.x;
    int wv   = tid >> 6;
    int lane = tid & 63;
    int quad = lane >> 4;
    int l16  = lane & 15;
    int pw   = w0 + l16;
    int ch0  = quad << 3;

    const unsigned short* xb = xTb + ((size_t)b << 18);
    const float* offp = off + (((b * 2 * K) * 64 + h) * 64) + pw;   // + k*8192 (dy), +4096 (dx)
    const float* mskp = msk + (((b * K) * 64 + h) * 64) + pw;       // + k*4096

    f32x4 acc[4];
    #pragma unroll
    for (int i = 0; i < 4; ++i) acc[i] = (f32x4){0.f, 0.f, 0.f, 0.f};

    // this wave's taps: k = wv, wv+4, ...
    int nt = (K - wv + 3) >> 2;
    int kyI = 0, kxI = wv;
    if (kxI >= kwid) { kxI -= kwid; kyI++; }

    auto adv = [&]() {
        kxI += 4;
        if (kxI >= kwid) { kxI -= kwid; kyI++; }
        if (kxI >= kwid) { kxI -= kwid; kyI++; }
    };

    // issue: compute corner weights + fire 8 corner gathers for one tap
    auto issue = [&](float dy, float dx, float mkv, float& w00, float& w01,
                     float& w10, float& w11, u16x8* G) {
        float py = (float)(h - pad + kyI) + dy;
        float px = (float)(pw - pad + kxI) + dx;
        float y0f = floorf(py), x0f = floorf(px);
        float wy = py - y0f, wx = px - x0f;
        int y0 = (int)y0f, x0 = (int)x0f;
        int y1 = y0 + 1,   x1 = x0 + 1;
        int y0c = min(max(y0, 0), 63), y1c = min(max(y1, 0), 63);
        int x0c = min(max(x0, 0), 63), x1c = min(max(x1, 0), 63);
        float fy0 = ((unsigned)y0 < 64u) ? (1.f - wy) * mkv : 0.f;
        float fy1 = ((unsigned)y1 < 64u) ? wy * mkv        : 0.f;
        float gx0 = ((unsigned)x0 < 64u) ? (1.f - wx)      : 0.f;
        float gx1 = ((unsigned)x1 < 64u) ? wx              : 0.f;
        w00 = fy0 * gx0; w01 = fy0 * gx1; w10 = fy1 * gx0; w11 = fy1 * gx1;
        int o00 = ((y0c << 6) + x0c) << 6;
        int o01 = ((y0c << 6) + x1c) << 6;
        int o10 = ((y1c << 6) + x0c) << 6;
        int o11 = ((y1c << 6) + x1c) << 6;
        G[0] = *(const u16x8*)(xb + o00 + ch0);
        G[1] = *(const u16x8*)(xb + o01 + ch0);
        G[2] = *(const u16x8*)(xb + o10 + ch0);
        G[3] = *(const u16x8*)(xb + o11 + ch0);
        G[4] = *(const u16x8*)(xb + o00 + 32 + ch0);
        G[5] = *(const u16x8*)(xb + o01 + 32 + ch0);
        G[6] = *(const u16x8*)(xb + o10 + 32 + ch0);
        G[7] = *(const u16x8*)(xb + o11 + 32 + ch0);
    };

    // consume: lerp -> A-frags, load B-frags, 8 MFMA
    auto consume = [&](float w00, float w01, float w10, float w11,
                       const u16x8* G, int kB) {
        const unsigned short* wpk = wp + (kB << 12);
        bf16x8 bfr[8];
        #pragma unroll
        for (int ct = 0; ct < 4; ++ct) {
            const unsigned short* wr = wpk + ((ct * 16 + l16) << 6);
            bfr[2 * ct]     = *(const bf16x8*)(wr + ch0);
            bfr[2 * ct + 1] = *(const bf16x8*)(wr + 32 + ch0);
        }
        union { bf16x8 v; unsigned short u[8]; } A0, A1;
        #pragma unroll
        for (int j = 0; j < 8; ++j) {
            float s0 = w00 * b2f(G[0][j]) + w01 * b2f(G[1][j])
                     + w10 * b2f(G[2][j]) + w11 * b2f(G[3][j]);
            float s1 = w00 * b2f(G[4][j]) + w01 * b2f(G[5][j])
                     + w10 * b2f(G[6][j]) + w11 * b2f(G[7][j]);
            A0.u[j] = f2bf(s0);
            A1.u[j] = f2bf(s1);
        }
        #pragma unroll
        for (int ct = 0; ct < 4; ++ct) {
            acc[ct] = __builtin_amdgcn_mfma_f32_16x16x32_bf16(A0.v, bfr[2 * ct],     acc[ct], 0, 0, 0);
            acc[ct] = __builtin_amdgcn_mfma_f32_16x16x32_bf16(A1.v, bfr[2 * ct + 1], acc[ct], 0, 0, 0);
        }
    };

    // ---- software pipeline: offsets 2 ahead, gathers 1 ahead ----
    float oyC, oxC, mkC, oyN = 0.f, oxN = 0.f, mkN = 0.f;
    float wA00, wA01, wA10, wA11, wB00, wB01, wB10, wB11;
    u16x8 GA[8], GB[8];

    int k0 = wv;
    oyC = offp[k0 * 8192]; oxC = offp[k0 * 8192 + 4096]; mkC = mskp[k0 * 4096];
    int kO = k0 + 4;
    if (nt > 1) { oyN = offp[kO * 8192]; oxN = offp[kO * 8192 + 4096]; mkN = mskp[kO * 4096]; }
    kO += 4;

    issue(oyC, oxC, mkC, wA00, wA01, wA10, wA11, GA);
    adv();
    oyC = oyN; oxC = oxN; mkC = mkN;

    int kB = k0;
    int i = 0;
    while (true) {
        if (i + 2 < nt) { oyN = offp[kO * 8192]; oxN = offp[kO * 8192 + 4096]; mkN = mskp[kO * 4096]; kO += 4; }
        if (i + 1 < nt) { issue(oyC, oxC, mkC, wB00, wB01, wB10, wB11, GB); adv(); }
        oyC = oyN; oxC = oxN; mkC = mkN;
        consume(wA00, wA01, wA10, wA11, GA, kB); kB += 4;
        if (++i >= nt) break;

        if (i + 2 < nt) { oyN = offp[kO * 8192]; oxN = offp[kO * 8192 + 4096]; mkN = mskp[kO * 4096]; kO += 4; }
        if (i + 1 < nt) { issue(oyC, oxC, mkC, wA00, wA01, wA10, wA11, GA); adv(); }
        oyC = oyN; oxC = oxN; mkC = mkN;
        consume(wB00, wB01, wB10, wB11, GB, kB); kB += 4;
        if (++i >= nt) break;
    }

    // ---- cross-wave reduction in LDS, then coalesced stores ----
    #pragma unroll
    for (int ct = 0; ct < 4; ++ct) {
        *(f32x4*)&red[wv * 1024 + ct * 256 + l16 * 16 + quad * 4] = acc[ct];
    }
    __syncthreads();

    {
        int o = tid >> 2, px4 = tid & 3;
        int base = (o >> 4) * 256 + (o & 15) * 16 + px4 * 4;
        f32x4 s0 = *(const f32x4*)&red[base];
        f32x4 s1 = *(const f32x4*)&red[1024 + base];
        f32x4 s2 = *(const f32x4*)&red[2048 + base];
        f32x4 s3 = *(const f32x4*)&red[3072 + base];
        f32x4 s;
        #pragma unroll
        for (int r = 0; r < 4; ++r) s[r] = (s0[r] + s1[r]) + (s2[r] + s3[r]);
        float* op = out + (((size_t)(b * 192 + obase + o)) * 64 + h) * 64 + w0 + px4 * 4;
        *(f32x4*)op = s;
    }
}

extern "C" void kernel_launch(void* const* d_in, const int* in_sizes, int n_in,
                              void* d_out, int out_size, void* d_ws, size_t ws_size,
                              hipStream_t stream) {
    const float* x    = (const float*)d_in[0];
    const float* f1   = (const float*)d_in[1];
    const float* off1 = (const float*)d_in[2];
    const float* msk1 = (const float*)d_in[3];
    const float* f2   = (const float*)d_in[4];
    const float* off2 = (const float*)d_in[5];
    const float* msk2 = (const float*)d_in[6];
    const float* f3   = (const float*)d_in[7];
    const float* off3 = (const float*)d_in[8];
    const float* msk3 = (const float*)d_in[9];
    float* out = (float*)d_out;

    // ws: xTb (2 MB bf16) | wp1 | wp2 | wp3 (bf16)
    unsigned short* xTb = (unsigned short*)d_ws;
    unsigned short* wp1 = xTb + 4 * 64 * 64 * 64;
    unsigned short* wp2 = wp1 + 9 * 4096;
    unsigned short* wp3 = wp2 + 25 * 4096;

    k_prep<<<dim3(1584), dim3(256), 0, stream>>>(x, f1, f2, f3, xTb, wp1, wp2, wp3);
    k_dcn<<<dim3(3072), dim3(256), 0, stream>>>(xTb,
                                                off1, msk1, wp1,
                                                off2, msk2, wp2,
                                                off3, msk3, wp3,
                                                out);
}

// Round 5
// 242.520 us; speedup vs baseline: 1.0627x; 1.0627x over previous
//
#include <hip/hip_runtime.h>
#include <hip/hip_bf16.h>

// DCNv2 inception, R5: occupancy + balance attack.
// 6144 balanced work units (per 16-px tile: 3x3 whole=9 taps; 5x5 split
// 13+12; 7x7 split 17+16+16), 4 independent waves per 256-thr block
// (no barriers/LDS in main loop), fp32 partials to ws + k_reduce sum.
// Inner loop = simple R3 body (R4's manual pipeline regressed: the
// limiter was resident-wave starvation, not per-wave ILP).

typedef __attribute__((ext_vector_type(8))) short bf16x8;
typedef __attribute__((ext_vector_type(8))) unsigned short u16x8;
typedef __attribute__((ext_vector_type(4))) float f32x4;

__device__ __forceinline__ float b2f(unsigned short u) {
    return __uint_as_float(((unsigned)u) << 16);
}
__device__ __forceinline__ unsigned short f2bf(float f) {
    __hip_bfloat16 h = __float2bfloat16(f);
    return *reinterpret_cast<unsigned short*>(&h);
}

// Merged prep: blocks [0,256): x[b][c][h][w] f32 -> xTb[b][h][w][c] bf16;
// blocks [256,1584): f[o][c][k] f32 -> wp[k][o][c] bf16 (all 3 filters).
__global__ __launch_bounds__(256) void k_prep(
    const float* __restrict__ x,
    const float* __restrict__ f1, const float* __restrict__ f2, const float* __restrict__ f3,
    unsigned short* __restrict__ xTb,
    unsigned short* __restrict__ wp1, unsigned short* __restrict__ wp2, unsigned short* __restrict__ wp3) {
    __shared__ float tile[64][65];
    int bid = blockIdx.x;
    int tid = threadIdx.x;
    if (bid < 256) {
        int b = bid >> 6, h = bid & 63;
        {
            int w = tid & 63, c4 = tid >> 6;
            const float* xp = x + (((b * 64) * 64 + h) * 64) + w;
            #pragma unroll
            for (int i = 0; i < 16; ++i) {
                int c = c4 * 16 + i;
                tile[c][w] = xp[c * 4096];
            }
        }
        __syncthreads();
        {
            int c = tid & 63, w4 = tid >> 6;
            unsigned short* op = xTb + (((b * 64 + h) * 64) * 64) + c;
            #pragma unroll
            for (int i = 0; i < 16; ++i) {
                int ww = w4 * 16 + i;
                op[ww * 64] = f2bf(tile[c][ww]);
            }
        }
    } else {
        int idx = (bid - 256) * 256 + tid;      // 83*4096 = 339968 total
        const float* f; unsigned short* wp; int K, rel;
        if (idx < 36864)       { f = f1; wp = wp1; K = 9;  rel = idx; }
        else if (idx < 139264) { f = f2; wp = wp2; K = 25; rel = idx - 36864; }
        else                   { f = f3; wp = wp3; K = 49; rel = idx - 139264; }
        int c = rel & 63;
        int o = (rel >> 6) & 63;
        int k = rel >> 12;
        wp[rel] = f2bf(f[(o * 64 + c) * K + k]);
    }
}

__global__ __launch_bounds__(256, 6) void k_dcn(
    const unsigned short* __restrict__ xTb,
    const float* __restrict__ off1, const float* __restrict__ msk1, const unsigned short* __restrict__ wp1,
    const float* __restrict__ off2, const float* __restrict__ msk2, const unsigned short* __restrict__ wp2,
    const float* __restrict__ off3, const float* __restrict__ msk3, const unsigned short* __restrict__ wp3,
    float* __restrict__ part) {

    int tid  = threadIdx.x;
    int wv   = tid >> 6;
    int lane = tid & 63;
    int quad = lane >> 4;
    int l16  = lane & 15;

    int unit = blockIdx.x * 4 + wv;      // 0..6143
    int tile = unit / 6;                 // 0..1023 (16 pixels each)
    int c    = unit - tile * 6;
    int b  = tile >> 8;
    int h  = (tile >> 2) & 63;
    int w0 = (tile & 3) << 4;

    // unit chunk -> (branch, tap range, initial ky/kx)  [compile-time consts]
    const float* off; const float* msk; const unsigned short* wp;
    int K, kwid, pad, s, e, ky, kx;
    switch (c) {
        case 0:  off = off1; msk = msk1; wp = wp1; K = 9;  kwid = 3; pad = 1; s = 0;  e = 9;  ky = 0; kx = 0; break;
        case 1:  off = off2; msk = msk2; wp = wp2; K = 25; kwid = 5; pad = 2; s = 0;  e = 13; ky = 0; kx = 0; break;
        case 2:  off = off2; msk = msk2; wp = wp2; K = 25; kwid = 5; pad = 2; s = 13; e = 25; ky = 2; kx = 3; break;
        case 3:  off = off3; msk = msk3; wp = wp3; K = 49; kwid = 7; pad = 3; s = 0;  e = 17; ky = 0; kx = 0; break;
        case 4:  off = off3; msk = msk3; wp = wp3; K = 49; kwid = 7; pad = 3; s = 17; e = 33; ky = 2; kx = 3; break;
        default: off = off3; msk = msk3; wp = wp3; K = 49; kwid = 7; pad = 3; s = 33; e = 49; ky = 4; kx = 5; break;
    }

    int pw  = w0 + l16;           // this lane's pixel w-coordinate
    int ch0 = quad << 3;          // A-fragment channel base

    const unsigned short* xb = xTb + ((size_t)b << 18);
    const float* offp = off + (((b * 2 * K) * 64 + h) * 64) + pw;   // + k*8192 (dy), +4096 (dx)
    const float* mskp = msk + (((b * K) * 64 + h) * 64) + pw;       // + k*4096

    f32x4 acc[4];
    #pragma unroll
    for (int i = 0; i < 4; ++i) acc[i] = (f32x4){0.f, 0.f, 0.f, 0.f};

    for (int k = s; k < e; ++k) {
        float dy = offp[k * 8192];
        float dx = offp[k * 8192 + 4096];
        float mk = mskp[k * 4096];
        float py = (float)(h - pad + ky) + dy;
        float px = (float)(pw - pad + kx) + dx;
        float y0f = floorf(py), x0f = floorf(px);
        float wy = py - y0f, wx = px - x0f;
        int y0 = (int)y0f, x0 = (int)x0f;
        int y1 = y0 + 1,   x1 = x0 + 1;
        int y0c = min(max(y0, 0), 63), y1c = min(max(y1, 0), 63);
        int x0c = min(max(x0, 0), 63), x1c = min(max(x1, 0), 63);
        float fy0 = ((unsigned)y0 < 64u) ? (1.f - wy) * mk : 0.f;
        float fy1 = ((unsigned)y1 < 64u) ? wy * mk        : 0.f;
        float gx0 = ((unsigned)x0 < 64u) ? (1.f - wx)      : 0.f;
        float gx1 = ((unsigned)x1 < 64u) ? wx              : 0.f;
        float w00 = fy0 * gx0, w01 = fy0 * gx1, w10 = fy1 * gx0, w11 = fy1 * gx1;

        int o00 = ((y0c << 6) + x0c) << 6;
        int o01 = ((y0c << 6) + x1c) << 6;
        int o10 = ((y1c << 6) + x0c) << 6;
        int o11 = ((y1c << 6) + x1c) << 6;

        u16x8 g00a = *(const u16x8*)(xb + o00 + ch0);
        u16x8 g01a = *(const u16x8*)(xb + o01 + ch0);
        u16x8 g10a = *(const u16x8*)(xb + o10 + ch0);
        u16x8 g11a = *(const u16x8*)(xb + o11 + ch0);
        u16x8 g00b = *(const u16x8*)(xb + o00 + 32 + ch0);
        u16x8 g01b = *(const u16x8*)(xb + o01 + 32 + ch0);
        u16x8 g10b = *(const u16x8*)(xb + o10 + 32 + ch0);
        u16x8 g11b = *(const u16x8*)(xb + o11 + 32 + ch0);

        union { bf16x8 v; unsigned short u[8]; } A0, A1;
        #pragma unroll
        for (int j = 0; j < 8; ++j) {
            float s0 = w00 * b2f(g00a[j]) + w01 * b2f(g01a[j])
                     + w10 * b2f(g10a[j]) + w11 * b2f(g11a[j]);
            float s1 = w00 * b2f(g00b[j]) + w01 * b2f(g01b[j])
                     + w10 * b2f(g10b[j]) + w11 * b2f(g11b[j]);
            A0.u[j] = f2bf(s0);
            A1.u[j] = f2bf(s1);
        }

        const unsigned short* wpk = wp + (k << 12);
        #pragma unroll
        for (int ct = 0; ct < 4; ++ct) {
            const unsigned short* wr = wpk + ((ct * 16 + l16) << 6);
            bf16x8 b0 = *(const bf16x8*)(wr + ch0);
            bf16x8 b1 = *(const bf16x8*)(wr + 32 + ch0);
            acc[ct] = __builtin_amdgcn_mfma_f32_16x16x32_bf16(A0.v, b0, acc[ct], 0, 0, 0);
            acc[ct] = __builtin_amdgcn_mfma_f32_16x16x32_bf16(A1.v, b1, acc[ct], 0, 0, 0);
        }

        if (++kx == kwid) { kx = 0; ++ky; }
    }

    // partial slab: part[unit][o][px], o=ct*16+l16 (D col), px=quad*4+r (D row)
    // per (ct): 64 lanes cover 256 contiguous floats -> fully coalesced dwordx4
    float* pp = part + (size_t)unit * 1024;
    #pragma unroll
    for (int ct = 0; ct < 4; ++ct) {
        *(f32x4*)&pp[(ct * 16 + l16) * 16 + quad * 4] = acc[ct];
    }
}

// Sum 1..3 partial slabs per output and write fp32 out (concat order 0,1,2).
__global__ __launch_bounds__(256) void k_reduce(const float* __restrict__ part,
                                                float* __restrict__ out) {
    int tid = blockIdx.x * 256 + threadIdx.x;   // 1024 tiles * 192 o * 4 groups
    int g   = tid & 3;
    int t2  = tid >> 2;
    int o   = t2 % 192;
    int tile = t2 / 192;
    int b  = tile >> 8;
    int h  = (tile >> 2) & 63;
    int w0 = (tile & 3) << 4;
    const float* P = part + (size_t)tile * 6144;
    int idx = o * 16 + g * 4;       // within a 1024-float slab (o' folded below)
    f32x4 v;
    if (o < 64) {
        v = *(const f32x4*)&P[idx];
    } else if (o < 128) {
        int ii = idx - 64 * 16;
        f32x4 a0 = *(const f32x4*)&P[1024 + ii];
        f32x4 a1 = *(const f32x4*)&P[2048 + ii];
        #pragma unroll
        for (int r = 0; r < 4; ++r) v[r] = a0[r] + a1[r];
    } else {
        int ii = idx - 128 * 16;
        f32x4 a0 = *(const f32x4*)&P[3072 + ii];
        f32x4 a1 = *(const f32x4*)&P[4096 + ii];
        f32x4 a2 = *(const f32x4*)&P[5120 + ii];
        #pragma unroll
        for (int r = 0; r < 4; ++r) v[r] = a0[r] + (a1[r] + a2[r]);
    }
    *(f32x4*)&out[(((size_t)b * 192 + o) * 64 + h) * 64 + w0 + g * 4] = v;
}

extern "C" void kernel_launch(void* const* d_in, const int* in_sizes, int n_in,
                              void* d_out, int out_size, void* d_ws, size_t ws_size,
                              hipStream_t stream) {
    const float* x    = (const float*)d_in[0];
    const float* f1   = (const float*)d_in[1];
    const float* off1 = (const float*)d_in[2];
    const float* msk1 = (const float*)d_in[3];
    const float* f2   = (const float*)d_in[4];
    const float* off2 = (const float*)d_in[5];
    const float* msk2 = (const float*)d_in[6];
    const float* f3   = (const float*)d_in[7];
    const float* off3 = (const float*)d_in[8];
    const float* msk3 = (const float*)d_in[9];
    float* out = (float*)d_out;

    // ws: xTb 2MB bf16 | wp1/wp2/wp3 bf16 (~0.66MB) | partials 24MB f32
    unsigned short* xTb = (unsigned short*)d_ws;
    unsigned short* wp1 = xTb + 4 * 64 * 64 * 64;        // 1,048,576 shorts
    unsigned short* wp2 = wp1 + 9 * 4096;
    unsigned short* wp3 = wp2 + 25 * 4096;
    float* part = (float*)(wp3 + 49 * 4096);             // 6144*1024 f32

    k_prep<<<dim3(1584), dim3(256), 0, stream>>>(x, f1, f2, f3, xTb, wp1, wp2, wp3);
    k_dcn<<<dim3(1536), dim3(256), 0, stream>>>(xTb,
                                                off1, msk1, wp1,
                                                off2, msk2, wp2,
                                                off3, msk3, wp3,
                                                part);
    k_reduce<<<dim3(3072), dim3(256), 0, stream>>>(part, out);
}

// Round 6
// 195.619 us; speedup vs baseline: 1.3175x; 1.2398x over previous
//
#include <hip/hip_runtime.h>
#include <hip/hip_bf16.h>

// DCNv2 inception, R6: LDS-window gather attack.
// Evidence: R3 (22% occ) and R5 (56% occ) both ~158 us -> shared resource
// saturated; counters rule out VALU/HBM/L2-BW/LDS. Theory: divergent-address
// vector gathers saturate the TA/L1 address path (~1 addr/cyc divergent).
// Fix: per 16-px tile, stage a 16-row x 30-col x 64-ch bf16 window of x in
// LDS (65,280 B) once, gather bilinear corners via ds_read_b128 (LDS crossbar
// handles divergence; +2-bank rotation padding). Valid-but-out-of-window
// corners (needs |off|>~4 sigma; ~never) fall back to global gathers.
// 4 waves = 4 compile-time tap-chunks (21/21/21/20 across the 3 branches);
// in-block LDS reduction replaces the k_reduce kernel + 24MB partials.

typedef __attribute__((ext_vector_type(8))) short bf16x8;
typedef __attribute__((ext_vector_type(8))) unsigned short u16x8;
typedef __attribute__((ext_vector_type(4))) float f32x4;

#define WR 16    // window rows
#define WC 30    // window cols
#define WS 68    // window position stride in shorts (34 dwords -> +2 bank rotate)
#define SLS 20   // slab o-stride in floats (2-way max on reduce)

__device__ __forceinline__ float b2f(unsigned short u) {
    return __uint_as_float(((unsigned)u) << 16);
}
__device__ __forceinline__ unsigned short f2bf(float f) {
    __hip_bfloat16 h = __float2bfloat16(f);
    return *reinterpret_cast<unsigned short*>(&h);
}

// Merged prep: blocks [0,256): x[b][c][h][w] f32 -> xTb[b][h][w][c] bf16;
// blocks [256,1584): f[o][c][k] f32 -> wp[k][o][c] bf16 (all 3 filters).
__global__ __launch_bounds__(256) void k_prep(
    const float* __restrict__ x,
    const float* __restrict__ f1, const float* __restrict__ f2, const float* __restrict__ f3,
    unsigned short* __restrict__ xTb,
    unsigned short* __restrict__ wp1, unsigned short* __restrict__ wp2, unsigned short* __restrict__ wp3) {
    __shared__ float tile[64][65];
    int bid = blockIdx.x;
    int tid = threadIdx.x;
    if (bid < 256) {
        int b = bid >> 6, h = bid & 63;
        {
            int w = tid & 63, c4 = tid >> 6;
            const float* xp = x + (((b * 64) * 64 + h) * 64) + w;
            #pragma unroll
            for (int i = 0; i < 16; ++i) {
                int c = c4 * 16 + i;
                tile[c][w] = xp[c * 4096];
            }
        }
        __syncthreads();
        {
            int c = tid & 63, w4 = tid >> 6;
            unsigned short* op = xTb + (((b * 64 + h) * 64) * 64) + c;
            #pragma unroll
            for (int i = 0; i < 16; ++i) {
                int ww = w4 * 16 + i;
                op[ww * 64] = f2bf(tile[c][ww]);
            }
        }
    } else {
        int idx = (bid - 256) * 256 + tid;      // 83*4096 = 339968 total
        const float* f; unsigned short* wp; int K, rel;
        if (idx < 36864)       { f = f1; wp = wp1; K = 9;  rel = idx; }
        else if (idx < 139264) { f = f2; wp = wp2; K = 25; rel = idx - 36864; }
        else                   { f = f3; wp = wp3; K = 49; rel = idx - 139264; }
        int c = rel & 63;
        int o = (rel >> 6) & 63;
        int k = rel >> 12;
        wp[rel] = f2bf(f[(o * 64 + c) * K + k]);
    }
}

// One tap-range of one branch, accumulating 16px x 64o into acc[4].
template<int KW, int PAD, int KS, int KE>
__device__ __forceinline__ void run_range(
    const float* __restrict__ offp, const float* __restrict__ mskp,
    const unsigned short* __restrict__ wp, const unsigned short* __restrict__ win,
    const unsigned short* __restrict__ xb,
    int h, int pw, int ylo, int cxlo, int ch0, int l16, f32x4 acc[4]) {

    #pragma unroll 2
    for (int k = KS; k < KE; ++k) {
        int ky = k / KW, kx = k - ky * KW;
        float dy = offp[k * 8192];
        float dx = offp[k * 8192 + 4096];
        float mk = mskp[k * 4096];
        float py = (float)(h - PAD + ky) + dy;
        float px = (float)(pw - PAD + kx) + dx;
        float y0f = floorf(py), x0f = floorf(px);
        float wy = py - y0f, wx = px - x0f;
        int y0 = (int)y0f, x0 = (int)x0f;
        int y1 = y0 + 1, x1 = x0 + 1;
        float fy0 = ((unsigned)y0 < 64u) ? (1.f - wy) * mk : 0.f;
        float fy1 = ((unsigned)y1 < 64u) ? wy * mk         : 0.f;
        float gx0 = ((unsigned)x0 < 64u) ? (1.f - wx)      : 0.f;
        float gx1 = ((unsigned)x1 < 64u) ? wx              : 0.f;
        float w00 = fy0 * gx0, w01 = fy0 * gx1, w10 = fy1 * gx0, w11 = fy1 * gx1;

        int r0 = y0 - ylo, r1 = r0 + 1;
        int c0 = x0 - cxlo, c1 = c0 + 1;
        bool oow = ((w00 != 0.f) & (((unsigned)r0 >= WR) | ((unsigned)c0 >= WC)))
                 | ((w01 != 0.f) & (((unsigned)r0 >= WR) | ((unsigned)c1 >= WC)))
                 | ((w10 != 0.f) & (((unsigned)r1 >= WR) | ((unsigned)c0 >= WC)))
                 | ((w11 != 0.f) & (((unsigned)r1 >= WR) | ((unsigned)c1 >= WC)));
        int r0c = min(max(r0, 0), WR - 1), r1c = min(max(r1, 0), WR - 1);
        int c0c = min(max(c0, 0), WC - 1), c1c = min(max(c1, 0), WC - 1);
        int p00 = (r0c * WC + c0c) * WS;
        int p01 = (r0c * WC + c1c) * WS;
        int p10 = (r1c * WC + c0c) * WS;
        int p11 = (r1c * WC + c1c) * WS;

        u16x8 g00a = *(const u16x8*)(win + p00 + ch0);
        u16x8 g01a = *(const u16x8*)(win + p01 + ch0);
        u16x8 g10a = *(const u16x8*)(win + p10 + ch0);
        u16x8 g11a = *(const u16x8*)(win + p11 + ch0);
        u16x8 g00b = *(const u16x8*)(win + p00 + 32 + ch0);
        u16x8 g01b = *(const u16x8*)(win + p01 + 32 + ch0);
        u16x8 g10b = *(const u16x8*)(win + p10 + 32 + ch0);
        u16x8 g11b = *(const u16x8*)(win + p11 + 32 + ch0);

        if (oow) {   // valid corner outside window: ~never (needs |off|>~4sd)
            int y0g = min(max(y0, 0), 63), y1g = min(max(y1, 0), 63);
            int x0g = min(max(x0, 0), 63), x1g = min(max(x1, 0), 63);
            int o00 = ((y0g << 6) + x0g) << 6;
            int o01 = ((y0g << 6) + x1g) << 6;
            int o10 = ((y1g << 6) + x0g) << 6;
            int o11 = ((y1g << 6) + x1g) << 6;
            g00a = *(const u16x8*)(xb + o00 + ch0);
            g01a = *(const u16x8*)(xb + o01 + ch0);
            g10a = *(const u16x8*)(xb + o10 + ch0);
            g11a = *(const u16x8*)(xb + o11 + ch0);
            g00b = *(const u16x8*)(xb + o00 + 32 + ch0);
            g01b = *(const u16x8*)(xb + o01 + 32 + ch0);
            g10b = *(const u16x8*)(xb + o10 + 32 + ch0);
            g11b = *(const u16x8*)(xb + o11 + 32 + ch0);
        }

        union { bf16x8 v; unsigned short u[8]; } A0, A1;
        #pragma unroll
        for (int j = 0; j < 8; ++j) {
            float s0 = w00 * b2f(g00a[j]) + w01 * b2f(g01a[j])
                     + w10 * b2f(g10a[j]) + w11 * b2f(g11a[j]);
            float s1 = w00 * b2f(g00b[j]) + w01 * b2f(g01b[j])
                     + w10 * b2f(g10b[j]) + w11 * b2f(g11b[j]);
            A0.u[j] = f2bf(s0);
            A1.u[j] = f2bf(s1);
        }

        const unsigned short* wpk = wp + (k << 12);
        #pragma unroll
        for (int ct = 0; ct < 4; ++ct) {
            const unsigned short* wr = wpk + ((ct * 16 + l16) << 6);
            bf16x8 b0 = *(const bf16x8*)(wr + ch0);
            bf16x8 b1 = *(const bf16x8*)(wr + 32 + ch0);
            acc[ct] = __builtin_amdgcn_mfma_f32_16x16x32_bf16(A0.v, b0, acc[ct], 0, 0, 0);
            acc[ct] = __builtin_amdgcn_mfma_f32_16x16x32_bf16(A1.v, b1, acc[ct], 0, 0, 0);
        }
    }
}

__global__ __launch_bounds__(256) void k_dcn(
    const unsigned short* __restrict__ xTb,
    const float* __restrict__ off1, const float* __restrict__ msk1, const unsigned short* __restrict__ wp1,
    const float* __restrict__ off2, const float* __restrict__ msk2, const unsigned short* __restrict__ wp2,
    const float* __restrict__ off3, const float* __restrict__ msk3, const unsigned short* __restrict__ wp3,
    float* __restrict__ out) {

    __shared__ __align__(16) unsigned char smem[WR * WC * WS * 2];   // 65,280 B
    unsigned short* win = (unsigned short*)smem;
    float* slab = (float*)smem;          // aliased after taps complete

    int tile = blockIdx.x;               // 0..1023
    int b  = tile >> 8;
    int h  = (tile >> 2) & 63;
    int w0 = (tile & 3) << 4;

    int tid  = threadIdx.x;
    int wv   = tid >> 6;
    int lane = tid & 63;
    int quad = lane >> 4;
    int l16  = lane & 15;
    int ylo  = h - 7, cxlo = w0 - 7;

    const unsigned short* xb = xTb + ((size_t)b << 18);

    // ---- stage window: 480 positions x 128 B, coalesced ----
    {
        int j = tid & 7;
        for (int p = tid >> 3; p < WR * WC; p += 32) {
            int r = p / WC, cc = p - r * WC;
            int y = min(max(ylo + r, 0), 63);
            int x = min(max(cxlo + cc, 0), 63);
            *(u16x8*)(win + p * WS + j * 8) =
                *(const u16x8*)(xb + (((y << 6) + x) << 6) + j * 8);
        }
    }
    __syncthreads();

    int pw  = w0 + l16;
    int ch0 = quad << 3;
    const float* o1p = off1 + (b * 18) * 4096 + (h << 6) + pw;
    const float* m1p = msk1 + (b * 9)  * 4096 + (h << 6) + pw;
    const float* o2p = off2 + (b * 50) * 4096 + (h << 6) + pw;
    const float* m2p = msk2 + (b * 25) * 4096 + (h << 6) + pw;
    const float* o3p = off3 + (b * 98) * 4096 + (h << 6) + pw;
    const float* m3p = msk3 + (b * 49) * 4096 + (h << 6) + pw;

    f32x4 accA[4], accB[4];
    #pragma unroll
    for (int i = 0; i < 4; ++i) { accA[i] = (f32x4){0,0,0,0}; accB[i] = (f32x4){0,0,0,0}; }
    int slabA, slabB = -1;

    // 4 balanced compile-time chunks over 83 taps: 21/21/21/20
    if (wv == 0) {
        run_range<3,1,0,9>  (o1p, m1p, wp1, win, xb, h, pw, ylo, cxlo, ch0, l16, accA);
        run_range<5,2,0,12> (o2p, m2p, wp2, win, xb, h, pw, ylo, cxlo, ch0, l16, accB);
        slabA = 0; slabB = 1;
    } else if (wv == 1) {
        run_range<5,2,12,25>(o2p, m2p, wp2, win, xb, h, pw, ylo, cxlo, ch0, l16, accA);
        run_range<7,3,0,8>  (o3p, m3p, wp3, win, xb, h, pw, ylo, cxlo, ch0, l16, accB);
        slabA = 2; slabB = 3;
    } else if (wv == 2) {
        run_range<7,3,8,29> (o3p, m3p, wp3, win, xb, h, pw, ylo, cxlo, ch0, l16, accA);
        slabA = 4;
    } else {
        run_range<7,3,29,49>(o3p, m3p, wp3, win, xb, h, pw, ylo, cxlo, ch0, l16, accA);
        slabA = 5;
    }

    __syncthreads();    // all waves done reading window; safe to alias as slab

    // slab layout: [s][o*SLS + quad*4], s in 0..5, 1280 floats per slab
    #pragma unroll
    for (int ct = 0; ct < 4; ++ct) {
        *(f32x4*)&slab[slabA * 1280 + (ct * 16 + l16) * SLS + quad * 4] = accA[ct];
    }
    if (slabB >= 0) {
        #pragma unroll
        for (int ct = 0; ct < 4; ++ct) {
            *(f32x4*)&slab[slabB * 1280 + (ct * 16 + l16) * SLS + quad * 4] = accB[ct];
        }
    }
    __syncthreads();

    // in-block reduce + store: 768 items = 192 o x 4 groups of 4 px
    for (int it = tid; it < 768; it += 256) {
        int g = it & 3;
        int o = it >> 2;            // 0..191 (concat order br0|br1|br2)
        int oo = o & 63;
        int base = oo * SLS + g * 4;
        f32x4 v;
        if (o < 64) {
            v = *(const f32x4*)&slab[base];
        } else if (o < 128) {
            f32x4 a0 = *(const f32x4*)&slab[1280 + base];
            f32x4 a1 = *(const f32x4*)&slab[2560 + base];
            #pragma unroll
            for (int r = 0; r < 4; ++r) v[r] = a0[r] + a1[r];
        } else {
            f32x4 a0 = *(const f32x4*)&slab[3840 + base];
            f32x4 a1 = *(const f32x4*)&slab[5120 + base];
            f32x4 a2 = *(const f32x4*)&slab[6400 + base];
            #pragma unroll
            for (int r = 0; r < 4; ++r) v[r] = a0[r] + (a1[r] + a2[r]);
        }
        *(f32x4*)&out[(((size_t)b * 192 + o) * 64 + h) * 64 + w0 + g * 4] = v;
    }
}

extern "C" void kernel_launch(void* const* d_in, const int* in_sizes, int n_in,
                              void* d_out, int out_size, void* d_ws, size_t ws_size,
                              hipStream_t stream) {
    const float* x    = (const float*)d_in[0];
    const float* f1   = (const float*)d_in[1];
    const float* off1 = (const float*)d_in[2];
    const float* msk1 = (const float*)d_in[3];
    const float* f2   = (const float*)d_in[4];
    const float* off2 = (const float*)d_in[5];
    const float* msk2 = (const float*)d_in[6];
    const float* f3   = (const float*)d_in[7];
    const float* off3 = (const float*)d_in[8];
    const float* msk3 = (const float*)d_in[9];
    float* out = (float*)d_out;

    // ws: xTb 2MB bf16 | wp1/wp2/wp3 bf16
    unsigned short* xTb = (unsigned short*)d_ws;
    unsigned short* wp1 = xTb + 4 * 64 * 64 * 64;
    unsigned short* wp2 = wp1 + 9 * 4096;
    unsigned short* wp3 = wp2 + 25 * 4096;

    k_prep<<<dim3(1584), dim3(256), 0, stream>>>(x, f1, f2, f3, xTb, wp1, wp2, wp3);
    k_dcn<<<dim3(1024), dim3(256), 0, stream>>>(xTb,
                                                off1, msk1, wp1,
                                                off2, msk2, wp2,
                                                off3, msk3, wp3,
                                                out);
}

// Round 7
// 180.255 us; speedup vs baseline: 1.4298x; 1.0852x over previous
//
#include <hip/hip_runtime.h>
#include <hip/hip_bf16.h>

// DCNv2 inception, R7: occupancy-per-window attack.
// R6 evidence: LDS window cut k_dcn 158->120 us but 64KB LDS caps residency
// at 2 blocks/CU x 4 waves = 8 waves/CU (Occ 21.6%, VALUBusy 24.6%) -- waves
// stall on per-tap latency with nothing to switch to. R7: SAME window, 8
// waves per block (512 thr) -> 16 waves/CU at the same LDS footprint.
// 83 taps in 8 compile-time chunks (9/11/11/3+8/10/10/10/11), 9 partial
// slabs reduced in-block (aliased over window). Lerp on float2 to invite
// v_pk_fma_f32.

typedef __attribute__((ext_vector_type(8))) short bf16x8;
typedef __attribute__((ext_vector_type(8))) unsigned short u16x8;
typedef __attribute__((ext_vector_type(4))) float f32x4;
typedef __attribute__((ext_vector_type(2))) float f32x2;

#define WR 16    // window rows
#define WC 30    // window cols
#define WS 68    // window position stride in shorts (34 dwords -> +2 bank rotate)
#define SLS 20   // slab o-stride in floats

__device__ __forceinline__ unsigned short f2bf(float f) {
    __hip_bfloat16 h = __float2bfloat16(f);
    return *reinterpret_cast<unsigned short*>(&h);
}
__device__ __forceinline__ f32x2 unpk(unsigned u) {
    f32x2 r;
    r[0] = __uint_as_float(u << 16);
    r[1] = __uint_as_float(u & 0xffff0000u);
    return r;
}

// Merged prep: blocks [0,256): x[b][c][h][w] f32 -> xTb[b][h][w][c] bf16;
// blocks [256,1584): f[o][c][k] f32 -> wp[k][o][c] bf16 (all 3 filters).
__global__ __launch_bounds__(256) void k_prep(
    const float* __restrict__ x,
    const float* __restrict__ f1, const float* __restrict__ f2, const float* __restrict__ f3,
    unsigned short* __restrict__ xTb,
    unsigned short* __restrict__ wp1, unsigned short* __restrict__ wp2, unsigned short* __restrict__ wp3) {
    __shared__ float tile[64][65];
    int bid = blockIdx.x;
    int tid = threadIdx.x;
    if (bid < 256) {
        int b = bid >> 6, h = bid & 63;
        {
            int w = tid & 63, c4 = tid >> 6;
            const float* xp = x + (((b * 64) * 64 + h) * 64) + w;
            #pragma unroll
            for (int i = 0; i < 16; ++i) {
                int c = c4 * 16 + i;
                tile[c][w] = xp[c * 4096];
            }
        }
        __syncthreads();
        {
            int c = tid & 63, w4 = tid >> 6;
            unsigned short* op = xTb + (((b * 64 + h) * 64) * 64) + c;
            #pragma unroll
            for (int i = 0; i < 16; ++i) {
                int ww = w4 * 16 + i;
                op[ww * 64] = f2bf(tile[c][ww]);
            }
        }
    } else {
        int idx = (bid - 256) * 256 + tid;      // 83*4096 = 339968 total
        const float* f; unsigned short* wp; int K, rel;
        if (idx < 36864)       { f = f1; wp = wp1; K = 9;  rel = idx; }
        else if (idx < 139264) { f = f2; wp = wp2; K = 25; rel = idx - 36864; }
        else                   { f = f3; wp = wp3; K = 49; rel = idx - 139264; }
        int c = rel & 63;
        int o = (rel >> 6) & 63;
        int k = rel >> 12;
        wp[rel] = f2bf(f[(o * 64 + c) * K + k]);
    }
}

// One tap-range of one branch, accumulating 16px x 64o into acc[4].
template<int KW, int PAD, int KS, int KE>
__device__ __forceinline__ void run_range(
    const float* __restrict__ offp, const float* __restrict__ mskp,
    const unsigned short* __restrict__ wp, const unsigned short* __restrict__ win,
    const unsigned short* __restrict__ xb,
    int h, int pw, int ylo, int cxlo, int ch0, int l16, f32x4 acc[4]) {

    #pragma unroll 2
    for (int k = KS; k < KE; ++k) {
        int ky = k / KW, kx = k - ky * KW;
        float dy = offp[k * 8192];
        float dx = offp[k * 8192 + 4096];
        float mk = mskp[k * 4096];
        float py = (float)(h - PAD + ky) + dy;
        float px = (float)(pw - PAD + kx) + dx;
        float y0f = floorf(py), x0f = floorf(px);
        float wy = py - y0f, wx = px - x0f;
        int y0 = (int)y0f, x0 = (int)x0f;
        int y1 = y0 + 1, x1 = x0 + 1;
        float fy0 = ((unsigned)y0 < 64u) ? (1.f - wy) * mk : 0.f;
        float fy1 = ((unsigned)y1 < 64u) ? wy * mk         : 0.f;
        float gx0 = ((unsigned)x0 < 64u) ? (1.f - wx)      : 0.f;
        float gx1 = ((unsigned)x1 < 64u) ? wx              : 0.f;
        float w00 = fy0 * gx0, w01 = fy0 * gx1, w10 = fy1 * gx0, w11 = fy1 * gx1;

        int r0 = y0 - ylo, r1 = r0 + 1;
        int c0 = x0 - cxlo, c1 = c0 + 1;
        bool oow = ((w00 != 0.f) & (((unsigned)r0 >= WR) | ((unsigned)c0 >= WC)))
                 | ((w01 != 0.f) & (((unsigned)r0 >= WR) | ((unsigned)c1 >= WC)))
                 | ((w10 != 0.f) & (((unsigned)r1 >= WR) | ((unsigned)c0 >= WC)))
                 | ((w11 != 0.f) & (((unsigned)r1 >= WR) | ((unsigned)c1 >= WC)));
        int r0c = min(max(r0, 0), WR - 1), r1c = min(max(r1, 0), WR - 1);
        int c0c = min(max(c0, 0), WC - 1), c1c = min(max(c1, 0), WC - 1);
        int p00 = (r0c * WC + c0c) * WS;
        int p01 = (r0c * WC + c1c) * WS;
        int p10 = (r1c * WC + c0c) * WS;
        int p11 = (r1c * WC + c1c) * WS;

        union U { u16x8 v; unsigned u[4]; };
        U g00a, g01a, g10a, g11a, g00b, g01b, g10b, g11b;
        g00a.v = *(const u16x8*)(win + p00 + ch0);
        g01a.v = *(const u16x8*)(win + p01 + ch0);
        g10a.v = *(const u16x8*)(win + p10 + ch0);
        g11a.v = *(const u16x8*)(win + p11 + ch0);
        g00b.v = *(const u16x8*)(win + p00 + 32 + ch0);
        g01b.v = *(const u16x8*)(win + p01 + 32 + ch0);
        g10b.v = *(const u16x8*)(win + p10 + 32 + ch0);
        g11b.v = *(const u16x8*)(win + p11 + 32 + ch0);

        if (oow) {   // valid corner outside window: needs |off|>~4sd, ~never
            int y0g = min(max(y0, 0), 63), y1g = min(max(y1, 0), 63);
            int x0g = min(max(x0, 0), 63), x1g = min(max(x1, 0), 63);
            int o00 = ((y0g << 6) + x0g) << 6;
            int o01 = ((y0g << 6) + x1g) << 6;
            int o10 = ((y1g << 6) + x0g) << 6;
            int o11 = ((y1g << 6) + x1g) << 6;
            g00a.v = *(const u16x8*)(xb + o00 + ch0);
            g01a.v = *(const u16x8*)(xb + o01 + ch0);
            g10a.v = *(const u16x8*)(xb + o10 + ch0);
            g11a.v = *(const u16x8*)(xb + o11 + ch0);
            g00b.v = *(const u16x8*)(xb + o00 + 32 + ch0);
            g01b.v = *(const u16x8*)(xb + o01 + 32 + ch0);
            g10b.v = *(const u16x8*)(xb + o10 + 32 + ch0);
            g11b.v = *(const u16x8*)(xb + o11 + 32 + ch0);
        }

        f32x2 W00 = {w00, w00}, W01 = {w01, w01}, W10 = {w10, w10}, W11 = {w11, w11};
        union { bf16x8 v; unsigned short u[8]; } A0, A1;
        #pragma unroll
        for (int j2 = 0; j2 < 4; ++j2) {
            f32x2 s0 = W00 * unpk(g00a.u[j2]) + W01 * unpk(g01a.u[j2])
                     + W10 * unpk(g10a.u[j2]) + W11 * unpk(g11a.u[j2]);
            f32x2 s1 = W00 * unpk(g00b.u[j2]) + W01 * unpk(g01b.u[j2])
                     + W10 * unpk(g10b.u[j2]) + W11 * unpk(g11b.u[j2]);
            A0.u[2 * j2]     = f2bf(s0[0]);
            A0.u[2 * j2 + 1] = f2bf(s0[1]);
            A1.u[2 * j2]     = f2bf(s1[0]);
            A1.u[2 * j2 + 1] = f2bf(s1[1]);
        }

        const unsigned short* wpk = wp + (k << 12);
        #pragma unroll
        for (int ct = 0; ct < 4; ++ct) {
            const unsigned short* wr = wpk + ((ct * 16 + l16) << 6);
            bf16x8 b0 = *(const bf16x8*)(wr + ch0);
            bf16x8 b1 = *(const bf16x8*)(wr + 32 + ch0);
            acc[ct] = __builtin_amdgcn_mfma_f32_16x16x32_bf16(A0.v, b0, acc[ct], 0, 0, 0);
            acc[ct] = __builtin_amdgcn_mfma_f32_16x16x32_bf16(A1.v, b1, acc[ct], 0, 0, 0);
        }
    }
}

__global__ __launch_bounds__(512, 4) void k_dcn(
    const unsigned short* __restrict__ xTb,
    const float* __restrict__ off1, const float* __restrict__ msk1, const unsigned short* __restrict__ wp1,
    const float* __restrict__ off2, const float* __restrict__ msk2, const unsigned short* __restrict__ wp2,
    const float* __restrict__ off3, const float* __restrict__ msk3, const unsigned short* __restrict__ wp3,
    float* __restrict__ out) {

    __shared__ __align__(16) unsigned char smem[WR * WC * WS * 2];   // 65,280 B
    unsigned short* win = (unsigned short*)smem;
    float* slab = (float*)smem;          // aliased after taps complete (9*1280*4 = 46,080 B)

    int tile = blockIdx.x;               // 0..1023
    int b  = tile >> 8;
    int h  = (tile >> 2) & 63;
    int w0 = (tile & 3) << 4;

    int tid  = threadIdx.x;
    int wv   = tid >> 6;                 // 0..7
    int lane = tid & 63;
    int quad = lane >> 4;
    int l16  = lane & 15;
    int ylo  = h - 7, cxlo = w0 - 7;

    const unsigned short* xb = xTb + ((size_t)b << 18);

    // ---- stage window: 480 positions x 128 B, coalesced, 512 threads ----
    {
        int j = tid & 7;
        for (int p = tid >> 3; p < WR * WC; p += 64) {
            int r = p / WC, cc = p - r * WC;
            int y = min(max(ylo + r, 0), 63);
            int x = min(max(cxlo + cc, 0), 63);
            *(u16x8*)(win + p * WS + j * 8) =
                *(const u16x8*)(xb + (((y << 6) + x) << 6) + j * 8);
        }
    }
    __syncthreads();

    int pw  = w0 + l16;
    int ch0 = quad << 3;
    const float* o1p = off1 + (b * 18) * 4096 + (h << 6) + pw;
    const float* m1p = msk1 + (b * 9)  * 4096 + (h << 6) + pw;
    const float* o2p = off2 + (b * 50) * 4096 + (h << 6) + pw;
    const float* m2p = msk2 + (b * 25) * 4096 + (h << 6) + pw;
    const float* o3p = off3 + (b * 98) * 4096 + (h << 6) + pw;
    const float* m3p = msk3 + (b * 49) * 4096 + (h << 6) + pw;

    f32x4 accA[4], accB[4];
    #pragma unroll
    for (int i = 0; i < 4; ++i) { accA[i] = (f32x4){0,0,0,0}; accB[i] = (f32x4){0,0,0,0}; }
    int slabA, slabB = -1;

    // 8 balanced compile-time chunks over 83 taps: 9/11/11/(3+8)/10/10/10/11
    switch (wv) {
        case 0:
            run_range<3,1,0,9>  (o1p, m1p, wp1, win, xb, h, pw, ylo, cxlo, ch0, l16, accA);
            slabA = 0; break;
        case 1:
            run_range<5,2,0,11> (o2p, m2p, wp2, win, xb, h, pw, ylo, cxlo, ch0, l16, accA);
            slabA = 1; break;
        case 2:
            run_range<5,2,11,22>(o2p, m2p, wp2, win, xb, h, pw, ylo, cxlo, ch0, l16, accA);
            slabA = 2; break;
        case 3:
            run_range<5,2,22,25>(o2p, m2p, wp2, win, xb, h, pw, ylo, cxlo, ch0, l16, accA);
            slabA = 3;
            run_range<7,3,0,8>  (o3p, m3p, wp3, win, xb, h, pw, ylo, cxlo, ch0, l16, accB);
            slabB = 4; break;
        case 4:
            run_range<7,3,8,18> (o3p, m3p, wp3, win, xb, h, pw, ylo, cxlo, ch0, l16, accA);
            slabA = 5; break;
        case 5:
            run_range<7,3,18,28>(o3p, m3p, wp3, win, xb, h, pw, ylo, cxlo, ch0, l16, accA);
            slabA = 6; break;
        case 6:
            run_range<7,3,28,38>(o3p, m3p, wp3, win, xb, h, pw, ylo, cxlo, ch0, l16, accA);
            slabA = 7; break;
        default:
            run_range<7,3,38,49>(o3p, m3p, wp3, win, xb, h, pw, ylo, cxlo, ch0, l16, accA);
            slabA = 8; break;
    }

    __syncthreads();    // all waves done reading window; safe to alias as slab

    #pragma unroll
    for (int ct = 0; ct < 4; ++ct) {
        *(f32x4*)&slab[slabA * 1280 + (ct * 16 + l16) * SLS + quad * 4] = accA[ct];
    }
    if (slabB >= 0) {
        #pragma unroll
        for (int ct = 0; ct < 4; ++ct) {
            *(f32x4*)&slab[slabB * 1280 + (ct * 16 + l16) * SLS + quad * 4] = accB[ct];
        }
    }
    __syncthreads();

    // in-block reduce + store: 768 items = 192 o x 4 groups of 4 px
    // br0 (o<64): slab 0; br1: slabs 1+2+3; br2: slabs 4..8
    for (int it = tid; it < 768; it += 512) {
        int g = it & 3;
        int o = it >> 2;            // 0..191 (concat order br0|br1|br2)
        int oo = o & 63;
        int base = oo * SLS + g * 4;
        f32x4 v;
        if (o < 64) {
            v = *(const f32x4*)&slab[base];
        } else if (o < 128) {
            f32x4 a0 = *(const f32x4*)&slab[1 * 1280 + base];
            f32x4 a1 = *(const f32x4*)&slab[2 * 1280 + base];
            f32x4 a2 = *(const f32x4*)&slab[3 * 1280 + base];
            #pragma unroll
            for (int r = 0; r < 4; ++r) v[r] = a0[r] + (a1[r] + a2[r]);
        } else {
            f32x4 a0 = *(const f32x4*)&slab[4 * 1280 + base];
            f32x4 a1 = *(const f32x4*)&slab[5 * 1280 + base];
            f32x4 a2 = *(const f32x4*)&slab[6 * 1280 + base];
            f32x4 a3 = *(const f32x4*)&slab[7 * 1280 + base];
            f32x4 a4 = *(const f32x4*)&slab[8 * 1280 + base];
            #pragma unroll
            for (int r = 0; r < 4; ++r) v[r] = (a0[r] + a1[r]) + (a2[r] + a3[r]) + a4[r];
        }
        *(f32x4*)&out[(((size_t)b * 192 + o) * 64 + h) * 64 + w0 + g * 4] = v;
    }
}

extern "C" void kernel_launch(void* const* d_in, const int* in_sizes, int n_in,
                              void* d_out, int out_size, void* d_ws, size_t ws_size,
                              hipStream_t stream) {
    const float* x    = (const float*)d_in[0];
    const float* f1   = (const float*)d_in[1];
    const float* off1 = (const float*)d_in[2];
    const float* msk1 = (const float*)d_in[3];
    const float* f2   = (const float*)d_in[4];
    const float* off2 = (const float*)d_in[5];
    const float* msk2 = (const float*)d_in[6];
    const float* f3   = (const float*)d_in[7];
    const float* off3 = (const float*)d_in[8];
    const float* msk3 = (const float*)d_in[9];
    float* out = (float*)d_out;

    // ws: xTb 2MB bf16 | wp1/wp2/wp3 bf16
    unsigned short* xTb = (unsigned short*)d_ws;
    unsigned short* wp1 = xTb + 4 * 64 * 64 * 64;
    unsigned short* wp2 = wp1 + 9 * 4096;
    unsigned short* wp3 = wp2 + 25 * 4096;

    k_prep<<<dim3(1584), dim3(256), 0, stream>>>(x, f1, f2, f3, xTb, wp1, wp2, wp3);
    k_dcn<<<dim3(1024), dim3(512), 0, stream>>>(xTb,
                                                off1, msk1, wp1,
                                                off2, msk2, wp2,
                                                off3, msk3, wp3,
                                                out);
}

// Round 8
// 172.710 us; speedup vs baseline: 1.4923x; 1.0437x over previous
//
#include <hip/hip_runtime.h>
#include <hip/hip_bf16.h>

// DCNv2 inception, R8: offset/mask batch-prefetch attack.
// R7 evidence: FETCH 24.6MB is dominated by the once-read offset/mask
// tensors (~16MB) -> every tap's chain starts with a ~900-cyc cold HBM
// load; per-tap effective time ~1130 cyc matches. Fix: per wave-range,
// prefetch ALL taps' (dy,dx,mask) into registers up front (one latency
// wait for ~30 concurrent loads), fully unroll the tap loop so arrays
// stay in registers and ds/B-frag loads pipeline across taps.
// Structure otherwise = R7 (LDS window, 8 waves/block, in-block reduce).

typedef __attribute__((ext_vector_type(8))) short bf16x8;
typedef __attribute__((ext_vector_type(8))) unsigned short u16x8;
typedef __attribute__((ext_vector_type(4))) float f32x4;
typedef __attribute__((ext_vector_type(2))) float f32x2;

#define WR 16    // window rows
#define WC 30    // window cols
#define WS 68    // window position stride in shorts (34 dwords -> +2 bank rotate)
#define SLS 20   // slab o-stride in floats

__device__ __forceinline__ unsigned short f2bf(float f) {
    __hip_bfloat16 h = __float2bfloat16(f);
    return *reinterpret_cast<unsigned short*>(&h);
}
__device__ __forceinline__ f32x2 unpk(unsigned u) {
    f32x2 r;
    r[0] = __uint_as_float(u << 16);
    r[1] = __uint_as_float(u & 0xffff0000u);
    return r;
}

// Merged prep: blocks [0,256): x[b][c][h][w] f32 -> xTb[b][h][w][c] bf16;
// blocks [256,1584): f[o][c][k] f32 -> wp[k][o][c] bf16 (all 3 filters).
__global__ __launch_bounds__(256) void k_prep(
    const float* __restrict__ x,
    const float* __restrict__ f1, const float* __restrict__ f2, const float* __restrict__ f3,
    unsigned short* __restrict__ xTb,
    unsigned short* __restrict__ wp1, unsigned short* __restrict__ wp2, unsigned short* __restrict__ wp3) {
    __shared__ float tile[64][65];
    int bid = blockIdx.x;
    int tid = threadIdx.x;
    if (bid < 256) {
        int b = bid >> 6, h = bid & 63;
        {
            int w = tid & 63, c4 = tid >> 6;
            const float* xp = x + (((b * 64) * 64 + h) * 64) + w;
            #pragma unroll
            for (int i = 0; i < 16; ++i) {
                int c = c4 * 16 + i;
                tile[c][w] = xp[c * 4096];
            }
        }
        __syncthreads();
        {
            int c = tid & 63, w4 = tid >> 6;
            unsigned short* op = xTb + (((b * 64 + h) * 64) * 64) + c;
            #pragma unroll
            for (int i = 0; i < 16; ++i) {
                int ww = w4 * 16 + i;
                op[ww * 64] = f2bf(tile[c][ww]);
            }
        }
    } else {
        int idx = (bid - 256) * 256 + tid;      // 83*4096 = 339968 total
        const float* f; unsigned short* wp; int K, rel;
        if (idx < 36864)       { f = f1; wp = wp1; K = 9;  rel = idx; }
        else if (idx < 139264) { f = f2; wp = wp2; K = 25; rel = idx - 36864; }
        else                   { f = f3; wp = wp3; K = 49; rel = idx - 139264; }
        int c = rel & 63;
        int o = (rel >> 6) & 63;
        int k = rel >> 12;
        wp[rel] = f2bf(f[(o * 64 + c) * K + k]);
    }
}

// One tap-range of one branch, accumulating 16px x 64o into acc[4].
template<int KW, int PAD, int KS, int KE>
__device__ __forceinline__ void run_range(
    const float* __restrict__ offp, const float* __restrict__ mskp,
    const unsigned short* __restrict__ wp, const unsigned short* __restrict__ win,
    const unsigned short* __restrict__ xb,
    int h, int pw, int ylo, int cxlo, int ch0, int l16, f32x4 acc[4]) {

    constexpr int NT = KE - KS;

    // ---- batch prefetch: all taps' params at once (one HBM latency) ----
    float dys[NT], dxs[NT], mks[NT];
    #pragma unroll
    for (int i = 0; i < NT; ++i) {
        dys[i] = offp[(KS + i) * 8192];
        dxs[i] = offp[(KS + i) * 8192 + 4096];
        mks[i] = mskp[(KS + i) * 4096];
    }

    #pragma unroll
    for (int i = 0; i < NT; ++i) {
        const int k = KS + i;
        const int ky = k / KW, kx = k - ky * KW;
        float dy = dys[i];
        float dx = dxs[i];
        float mk = mks[i];
        float py = (float)(h - PAD + ky) + dy;
        float px = (float)(pw - PAD + kx) + dx;
        float y0f = floorf(py), x0f = floorf(px);
        float wy = py - y0f, wx = px - x0f;
        int y0 = (int)y0f, x0 = (int)x0f;
        int y1 = y0 + 1, x1 = x0 + 1;
        float fy0 = ((unsigned)y0 < 64u) ? (1.f - wy) * mk : 0.f;
        float fy1 = ((unsigned)y1 < 64u) ? wy * mk         : 0.f;
        float gx0 = ((unsigned)x0 < 64u) ? (1.f - wx)      : 0.f;
        float gx1 = ((unsigned)x1 < 64u) ? wx              : 0.f;
        float w00 = fy0 * gx0, w01 = fy0 * gx1, w10 = fy1 * gx0, w11 = fy1 * gx1;

        int r0 = y0 - ylo, r1 = r0 + 1;
        int c0 = x0 - cxlo, c1 = c0 + 1;
        bool oow = ((w00 != 0.f) & (((unsigned)r0 >= WR) | ((unsigned)c0 >= WC)))
                 | ((w01 != 0.f) & (((unsigned)r0 >= WR) | ((unsigned)c1 >= WC)))
                 | ((w10 != 0.f) & (((unsigned)r1 >= WR) | ((unsigned)c0 >= WC)))
                 | ((w11 != 0.f) & (((unsigned)r1 >= WR) | ((unsigned)c1 >= WC)));
        int r0c = min(max(r0, 0), WR - 1), r1c = min(max(r1, 0), WR - 1);
        int c0c = min(max(c0, 0), WC - 1), c1c = min(max(c1, 0), WC - 1);
        int p00 = (r0c * WC + c0c) * WS;
        int p01 = (r0c * WC + c1c) * WS;
        int p10 = (r1c * WC + c0c) * WS;
        int p11 = (r1c * WC + c1c) * WS;

        union U { u16x8 v; unsigned u[4]; };
        U g00a, g01a, g10a, g11a, g00b, g01b, g10b, g11b;
        g00a.v = *(const u16x8*)(win + p00 + ch0);
        g01a.v = *(const u16x8*)(win + p01 + ch0);
        g10a.v = *(const u16x8*)(win + p10 + ch0);
        g11a.v = *(const u16x8*)(win + p11 + ch0);
        g00b.v = *(const u16x8*)(win + p00 + 32 + ch0);
        g01b.v = *(const u16x8*)(win + p01 + 32 + ch0);
        g10b.v = *(const u16x8*)(win + p10 + 32 + ch0);
        g11b.v = *(const u16x8*)(win + p11 + 32 + ch0);

        if (oow) {   // valid corner outside window: needs |off|>~4sd, ~never
            int y0g = min(max(y0, 0), 63), y1g = min(max(y1, 0), 63);
            int x0g = min(max(x0, 0), 63), x1g = min(max(x1, 0), 63);
            int o00 = ((y0g << 6) + x0g) << 6;
            int o01 = ((y0g << 6) + x1g) << 6;
            int o10 = ((y1g << 6) + x0g) << 6;
            int o11 = ((y1g << 6) + x1g) << 6;
            g00a.v = *(const u16x8*)(xb + o00 + ch0);
            g01a.v = *(const u16x8*)(xb + o01 + ch0);
            g10a.v = *(const u16x8*)(xb + o10 + ch0);
            g11a.v = *(const u16x8*)(xb + o11 + ch0);
            g00b.v = *(const u16x8*)(xb + o00 + 32 + ch0);
            g01b.v = *(const u16x8*)(xb + o01 + 32 + ch0);
            g10b.v = *(const u16x8*)(xb + o10 + 32 + ch0);
            g11b.v = *(const u16x8*)(xb + o11 + 32 + ch0);
        }

        f32x2 W00 = {w00, w00}, W01 = {w01, w01}, W10 = {w10, w10}, W11 = {w11, w11};
        union { bf16x8 v; unsigned short u[8]; } A0, A1;
        #pragma unroll
        for (int j2 = 0; j2 < 4; ++j2) {
            f32x2 s0 = W00 * unpk(g00a.u[j2]) + W01 * unpk(g01a.u[j2])
                     + W10 * unpk(g10a.u[j2]) + W11 * unpk(g11a.u[j2]);
            f32x2 s1 = W00 * unpk(g00b.u[j2]) + W01 * unpk(g01b.u[j2])
                     + W10 * unpk(g10b.u[j2]) + W11 * unpk(g11b.u[j2]);
            A0.u[2 * j2]     = f2bf(s0[0]);
            A0.u[2 * j2 + 1] = f2bf(s0[1]);
            A1.u[2 * j2]     = f2bf(s1[0]);
            A1.u[2 * j2 + 1] = f2bf(s1[1]);
        }

        const unsigned short* wpk = wp + (k << 12);
        #pragma unroll
        for (int ct = 0; ct < 4; ++ct) {
            const unsigned short* wr = wpk + ((ct * 16 + l16) << 6);
            bf16x8 b0 = *(const bf16x8*)(wr + ch0);
            bf16x8 b1 = *(const bf16x8*)(wr + 32 + ch0);
            acc[ct] = __builtin_amdgcn_mfma_f32_16x16x32_bf16(A0.v, b0, acc[ct], 0, 0, 0);
            acc[ct] = __builtin_amdgcn_mfma_f32_16x16x32_bf16(A1.v, b1, acc[ct], 0, 0, 0);
        }
    }
}

__global__ __launch_bounds__(512, 4) void k_dcn(
    const unsigned short* __restrict__ xTb,
    const float* __restrict__ off1, const float* __restrict__ msk1, const unsigned short* __restrict__ wp1,
    const float* __restrict__ off2, const float* __restrict__ msk2, const unsigned short* __restrict__ wp2,
    const float* __restrict__ off3, const float* __restrict__ msk3, const unsigned short* __restrict__ wp3,
    float* __restrict__ out) {

    __shared__ __align__(16) unsigned char smem[WR * WC * WS * 2];   // 65,280 B
    unsigned short* win = (unsigned short*)smem;
    float* slab = (float*)smem;          // aliased after taps complete (9*1280*4 = 46,080 B)

    int tile = blockIdx.x;               // 0..1023
    int b  = tile >> 8;
    int h  = (tile >> 2) & 63;
    int w0 = (tile & 3) << 4;

    int tid  = threadIdx.x;
    int wv   = tid >> 6;                 // 0..7
    int lane = tid & 63;
    int quad = lane >> 4;
    int l16  = lane & 15;
    int ylo  = h - 7, cxlo = w0 - 7;

    const unsigned short* xb = xTb + ((size_t)b << 18);

    // ---- stage window: 480 positions x 128 B, coalesced, 512 threads ----
    {
        int j = tid & 7;
        for (int p = tid >> 3; p < WR * WC; p += 64) {
            int r = p / WC, cc = p - r * WC;
            int y = min(max(ylo + r, 0), 63);
            int x = min(max(cxlo + cc, 0), 63);
            *(u16x8*)(win + p * WS + j * 8) =
                *(const u16x8*)(xb + (((y << 6) + x) << 6) + j * 8);
        }
    }
    __syncthreads();

    int pw  = w0 + l16;
    int ch0 = quad << 3;
    const float* o1p = off1 + (b * 18) * 4096 + (h << 6) + pw;
    const float* m1p = msk1 + (b * 9)  * 4096 + (h << 6) + pw;
    const float* o2p = off2 + (b * 50) * 4096 + (h << 6) + pw;
    const float* m2p = msk2 + (b * 25) * 4096 + (h << 6) + pw;
    const float* o3p = off3 + (b * 98) * 4096 + (h << 6) + pw;
    const float* m3p = msk3 + (b * 49) * 4096 + (h << 6) + pw;

    f32x4 accA[4], accB[4];
    #pragma unroll
    for (int i = 0; i < 4; ++i) { accA[i] = (f32x4){0,0,0,0}; accB[i] = (f32x4){0,0,0,0}; }
    int slabA, slabB = -1;

    // 8 balanced compile-time chunks over 83 taps: 9/11/11/(3+8)/10/10/10/11
    switch (wv) {
        case 0:
            run_range<3,1,0,9>  (o1p, m1p, wp1, win, xb, h, pw, ylo, cxlo, ch0, l16, accA);
            slabA = 0; break;
        case 1:
            run_range<5,2,0,11> (o2p, m2p, wp2, win, xb, h, pw, ylo, cxlo, ch0, l16, accA);
            slabA = 1; break;
        case 2:
            run_range<5,2,11,22>(o2p, m2p, wp2, win, xb, h, pw, ylo, cxlo, ch0, l16, accA);
            slabA = 2; break;
        case 3:
            run_range<5,2,22,25>(o2p, m2p, wp2, win, xb, h, pw, ylo, cxlo, ch0, l16, accA);
            slabA = 3;
            run_range<7,3,0,8>  (o3p, m3p, wp3, win, xb, h, pw, ylo, cxlo, ch0, l16, accB);
            slabB = 4; break;
        case 4:
            run_range<7,3,8,18> (o3p, m3p, wp3, win, xb, h, pw, ylo, cxlo, ch0, l16, accA);
            slabA = 5; break;
        case 5:
            run_range<7,3,18,28>(o3p, m3p, wp3, win, xb, h, pw, ylo, cxlo, ch0, l16, accA);
            slabA = 6; break;
        case 6:
            run_range<7,3,28,38>(o3p, m3p, wp3, win, xb, h, pw, ylo, cxlo, ch0, l16, accA);
            slabA = 7; break;
        default:
            run_range<7,3,38,49>(o3p, m3p, wp3, win, xb, h, pw, ylo, cxlo, ch0, l16, accA);
            slabA = 8; break;
    }

    __syncthreads();    // all waves done reading window; safe to alias as slab

    #pragma unroll
    for (int ct = 0; ct < 4; ++ct) {
        *(f32x4*)&slab[slabA * 1280 + (ct * 16 + l16) * SLS + quad * 4] = accA[ct];
    }
    if (slabB >= 0) {
        #pragma unroll
        for (int ct = 0; ct < 4; ++ct) {
            *(f32x4*)&slab[slabB * 1280 + (ct * 16 + l16) * SLS + quad * 4] = accB[ct];
        }
    }
    __syncthreads();

    // in-block reduce + store: 768 items = 192 o x 4 groups of 4 px
    // br0 (o<64): slab 0; br1: slabs 1+2+3; br2: slabs 4..8
    for (int it = tid; it < 768; it += 512) {
        int g = it & 3;
        int o = it >> 2;            // 0..191 (concat order br0|br1|br2)
        int oo = o & 63;
        int base = oo * SLS + g * 4;
        f32x4 v;
        if (o < 64) {
            v = *(const f32x4*)&slab[base];
        } else if (o < 128) {
            f32x4 a0 = *(const f32x4*)&slab[1 * 1280 + base];
            f32x4 a1 = *(const f32x4*)&slab[2 * 1280 + base];
            f32x4 a2 = *(const f32x4*)&slab[3 * 1280 + base];
            #pragma unroll
            for (int r = 0; r < 4; ++r) v[r] = a0[r] + (a1[r] + a2[r]);
        } else {
            f32x4 a0 = *(const f32x4*)&slab[4 * 1280 + base];
            f32x4 a1 = *(const f32x4*)&slab[5 * 1280 + base];
            f32x4 a2 = *(const f32x4*)&slab[6 * 1280 + base];
            f32x4 a3 = *(const f32x4*)&slab[7 * 1280 + base];
            f32x4 a4 = *(const f32x4*)&slab[8 * 1280 + base];
            #pragma unroll
            for (int r = 0; r < 4; ++r) v[r] = (a0[r] + a1[r]) + (a2[r] + a3[r]) + a4[r];
        }
        *(f32x4*)&out[(((size_t)b * 192 + o) * 64 + h) * 64 + w0 + g * 4] = v;
    }
}

extern "C" void kernel_launch(void* const* d_in, const int* in_sizes, int n_in,
                              void* d_out, int out_size, void* d_ws, size_t ws_size,
                              hipStream_t stream) {
    const float* x    = (const float*)d_in[0];
    const float* f1   = (const float*)d_in[1];
    const float* off1 = (const float*)d_in[2];
    const float* msk1 = (const float*)d_in[3];
    const float* f2   = (const float*)d_in[4];
    const float* off2 = (const float*)d_in[5];
    const float* msk2 = (const float*)d_in[6];
    const float* f3   = (const float*)d_in[7];
    const float* off3 = (const float*)d_in[8];
    const float* msk3 = (const float*)d_in[9];
    float* out = (float*)d_out;

    // ws: xTb 2MB bf16 | wp1/wp2/wp3 bf16
    unsigned short* xTb = (unsigned short*)d_ws;
    unsigned short* wp1 = xTb + 4 * 64 * 64 * 64;
    unsigned short* wp2 = wp1 + 9 * 4096;
    unsigned short* wp3 = wp2 + 25 * 4096;

    k_prep<<<dim3(1584), dim3(256), 0, stream>>>(x, f1, f2, f3, xTb, wp1, wp2, wp3);
    k_dcn<<<dim3(1024), dim3(512), 0, stream>>>(xTb,
                                                off1, msk1, wp1,
                                                off2, msk2, wp2,
                                                off3, msk3, wp3,
                                                out);
}